// Round 7
// baseline (520.800 us; speedup 1.0000x reference)
//
#include <hip/hip_runtime.h>
#include <hip/hip_bf16.h>
#include <hip/hip_cooperative_groups.h>

namespace cg = cooperative_groups;

#define H 64
#define SCAN_CHUNK 512
#define NB1 512          // edge partition blocks (hist = 256*NB1 per direction)

typedef unsigned short u16;
typedef unsigned int u32;
typedef unsigned char u8;
typedef __attribute__((ext_vector_type(8))) __bf16 bf16x8;
typedef __attribute__((ext_vector_type(4))) float f32x4;
typedef __attribute__((ext_vector_type(2))) float f32x2;

__device__ __forceinline__ float bflo(u32 u) {
    return __builtin_bit_cast(float, u << 16);
}
__device__ __forceinline__ float bfhi(u32 u) {
    return __builtin_bit_cast(float, u & 0xffff0000u);
}
__device__ __forceinline__ u16 bf16rne(float f) {
    u32 u = __builtin_bit_cast(u32, f);
    return (u16)((u + 0x7FFFu + ((u >> 16) & 1u)) >> 16);
}
__device__ __forceinline__ u8 fp8enc(float f) {   // OCP e4m3, input pre-scaled
    return (u8)(__builtin_amdgcn_cvt_pk_fp8_f32(f, 0.0f, 0, false) & 0xFF);
}

// ---------------------------------------------------------------------------
// Fused: blocks [0,NB1) = edge histogram (LDS atomics, bucket-major out);
// rest: table conversion gene/dis -> bf16 + fp8(x16, 64 B rows).
// ---------------------------------------------------------------------------
__global__ __launch_bounds__(256) void fused_count_convert_kernel(
    const int* __restrict__ es, const int* __restrict__ ed,
    int* __restrict__ histD, int* __restrict__ histG,
    int ne, int shiftD, int shiftG,
    const float* __restrict__ a, u16* __restrict__ oa, u32* __restrict__ oa8,
    long long na4,
    const float* __restrict__ b, u16* __restrict__ ob, u32* __restrict__ ob8,
    long long nb4)
{
    if (blockIdx.x < NB1) {
        __shared__ int lhd[256], lhg[256];
        const int tid = threadIdx.x;
        lhd[tid] = 0; lhg[tid] = 0;
        __syncthreads();
        const int chunk = (ne + NB1 - 1) / NB1;
        const int e0 = blockIdx.x * chunk;
        const int e1 = min(e0 + chunk, ne);
        for (int e = e0 + tid; e < e1; e += 256) {
            atomicAdd(&lhd[ed[e] >> shiftD], 1);
            atomicAdd(&lhg[es[e] >> shiftG], 1);
        }
        __syncthreads();
        histD[tid * NB1 + blockIdx.x] = lhd[tid];
        histG[tid * NB1 + blockIdx.x] = lhg[tid];
        return;
    }
    long long i = (long long)(blockIdx.x - NB1) * 256 + threadIdx.x;
    const float* src; u16* dst; u32* dst8; long long q;
    if (i < na4) { src = a; dst = oa; dst8 = oa8; q = i; }
    else if (i < na4 + nb4) { src = b; dst = ob; dst8 = ob8; q = i - na4; }
    else return;
    float4 v = *(const float4*)&src[q * 4];
    ushort4 o;
    o.x = bf16rne(v.x); o.y = bf16rne(v.y);
    o.z = bf16rne(v.z); o.w = bf16rne(v.w);
    *(ushort4*)&dst[q * 4] = o;
    int r = 0;
    r = __builtin_amdgcn_cvt_pk_fp8_f32(v.x * 16.0f, v.y * 16.0f, r, false);
    r = __builtin_amdgcn_cvt_pk_fp8_f32(v.z * 16.0f, v.w * 16.0f, r, true);
    dst8[q] = (u32)r;
}

// ---------------------------------------------------------------------------
// COOPERATIVE preproc: scan-reduce | scan-apply | part-scatter | csr-build
// in ONE kernel with grid.sync() between phases (identical semantics to the
// previous 4 dispatches; saves 3 launch+drain boundaries). Grid is exactly
// 512 blocks x 256 threads: 2 blocks/CU co-resident, 4.1 KB LDS (aliased
// per phase), well inside cooperative-launch capacity.
// ---------------------------------------------------------------------------
__global__ __launch_bounds__(256) void preproc_coop_kernel(
    int* __restrict__ histD, int* __restrict__ histG, int n1,
    int* __restrict__ baseD, int* __restrict__ baseG,
    const int* __restrict__ es, const int* __restrict__ ed,
    u32* __restrict__ pairD, u32* __restrict__ pairG,
    int ne, int shiftD, int shiftG,
    int* __restrict__ rowD, int* __restrict__ idxD, int nd, int nbktD,
    int* __restrict__ rowG, int* __restrict__ idxG, int ng, int nbktG,
    int* __restrict__ partial,
    u32* __restrict__ pad0, u32* __restrict__ pad1,
    u32* __restrict__ pad2, u32* __restrict__ pad3)
{
    cg::grid_group grid = cg::this_grid();
    __shared__ int sh[1028];          // aliased: sExcl/curD+curG/lcnt+lcur, +ws
    const int tid = threadIdx.x;
    const int b = blockIdx.x;
    const int lane = tid & 63, wid = tid >> 6;
    const int B1 = n1 / SCAN_CHUNK;   // 256
    const int nbtot = 2 * B1;         // 512 == gridDim.x

    // ---- Phase A: per-chunk reduce -> partial[512]; zero fp8 pad rows ----
    {
        if (b == 0) {
            if (tid < 16) pad0[tid] = 0;
            else if (tid < 32) pad1[tid - 16] = 0;
            else if (tid < 48) pad2[tid - 32] = 0;
            else if (tid < 64) pad3[tid - 48] = 0;
        }
        const int* a = (b < B1) ? histD : histG;
        int base = ((b < B1) ? b : b - B1) * SCAN_CHUNK;
        int i0 = base + 2 * tid;          // n1 % SCAN_CHUNK == 0: no bounds
        int v = a[i0] + a[i0 + 1];
        #pragma unroll
        for (int off = 32; off > 0; off >>= 1) v += __shfl_down(v, off, 64);
        if (lane == 0) sh[1024 + wid] = v;
        __syncthreads();
        if (tid == 0) partial[b] = sh[1024] + sh[1025] + sh[1026] + sh[1027];
    }
    grid.sync();

    // ---- Phase B: scan-apply -> baseD/baseG cursors + totals ----
    {
        int* sExcl = sh;
        int* ws = sh + 1024;
        int j0 = 4 * tid;
        int p0 = (j0 + 0 < nbtot) ? partial[j0 + 0] : 0;
        int p1 = (j0 + 1 < nbtot) ? partial[j0 + 1] : 0;
        int p2 = (j0 + 2 < nbtot) ? partial[j0 + 2] : 0;
        int p3 = (j0 + 3 < nbtot) ? partial[j0 + 3] : 0;
        int psum = p0 + p1 + p2 + p3;
        int P = psum;
        #pragma unroll
        for (int off = 1; off < 64; off <<= 1) {
            int u = __shfl_up(P, off, 64);
            if (lane >= off) P += u;
        }
        if (lane == 63) ws[wid] = P;
        __syncthreads();
        int wbase = 0;
        #pragma unroll
        for (int w = 0; w < 4; ++w) wbase += (w < wid) ? ws[w] : 0;
        int e = wbase + (P - psum);
        sExcl[j0 + 0] = e;
        sExcl[j0 + 1] = e + p0;
        sExcl[j0 + 2] = e + p0 + p1;
        sExcl[j0 + 3] = e + p0 + p1 + p2;
        __syncthreads();

        int tot1 = sExcl[B1 - 1] + partial[B1 - 1];
        int myOff = sExcl[b] - ((b >= B1) ? tot1 : 0);
        if (b == 0 && tid == 0) {
            int tot2 = sExcl[nbtot - 1] + partial[nbtot - 1] - tot1;
            baseD[n1] = tot1;
            baseG[n1] = tot2;
        }
        __syncthreads();

        const int* a; int* out; int base;
        if (b < B1) { a = histD; out = baseD; base = b * SCAN_CHUNK; }
        else        { a = histG; out = baseG; base = (b - B1) * SCAN_CHUNK; }
        int i0 = base + 2 * tid, i1 = i0 + 1;
        int x0 = a[i0];
        int x1 = a[i1];
        int p = x0 + x1;
        int Q = p;
        #pragma unroll
        for (int off = 1; off < 64; off <<= 1) {
            int u = __shfl_up(Q, off, 64);
            if (lane >= off) Q += u;
        }
        if (lane == 63) ws[wid] = Q;
        __syncthreads();
        int waveBase = 0;
        #pragma unroll
        for (int w = 0; w < 4; ++w) waveBase += (w < wid) ? ws[w] : 0;
        int off0 = myOff + waveBase + (Q - p);
        out[i0] = off0;
        out[i1] = off0 + x0;
    }
    grid.sync();

    // ---- Phase C: edge pair partition (LDS cursors) ----
    {
        int* curD = sh;
        int* curG = sh + 256;
        curD[tid] = baseD[tid * NB1 + b];
        curG[tid] = baseG[tid * NB1 + b];
        __syncthreads();
        const int maskD = (1 << shiftD) - 1;
        const int maskG = (1 << shiftG) - 1;
        const int chunk = (ne + NB1 - 1) / NB1;
        const int e0 = b * chunk;
        const int e1 = min(e0 + chunk, ne);
        for (int e = e0 + tid; e < e1; e += 256) {
            int s = es[e], d = ed[e];
            int pD = atomicAdd(&curD[d >> shiftD], 1);
            pairD[pD] = ((u32)(d & maskD) << 17) | (u32)s;
            int pG = atomicAdd(&curG[s >> shiftG], 1);
            pairG[pG] = ((u32)(s & maskG) << 17) | (u32)d;
        }
    }
    grid.sync();

    // ---- Phase D: CSR finalize (one block per bucket; last phase) ----
    {
        const int j = b & 255;
        const int isG = b >> 8;
        const u32* pair; const int* base; int* row; int* idx; int n, shift, nbkt;
        if (isG) { pair = pairG; base = baseG; row = rowG; idx = idxG; n = ng; shift = shiftG + 0; nbkt = nbktG; }
        else     { pair = pairD; base = baseD; row = rowD; idx = idxD; n = nd; shift = shiftD + 0; nbkt = nbktD; }
        if (j < nbkt) {
            int* lcnt = sh;
            int* lcur = sh + 512;
            int* ws = sh + 1024;
            const int nLo = j << shift;
            const int nHi = min(nLo + (1 << shift), n);
            const int range = nHi - nLo;               // <= 512
            const int segBase = base[j * NB1];
            const int segEnd  = base[(j + 1) * NB1];

            lcnt[tid] = 0; lcnt[tid + 256] = 0;
            __syncthreads();
            for (int t = segBase + tid; t < segEnd; t += 256)
                atomicAdd(&lcnt[pair[t] >> 17], 1);
            __syncthreads();

            int i0 = 2 * tid, i1 = i0 + 1;
            int c0 = (i0 < range) ? lcnt[i0] : 0;
            int c1 = (i1 < range) ? lcnt[i1] : 0;
            int p = c0 + c1;
            int P = p;
            #pragma unroll
            for (int off = 1; off < 64; off <<= 1) {
                int u = __shfl_up(P, off, 64);
                if (lane >= off) P += u;
            }
            if (lane == 63) ws[wid] = P;
            __syncthreads();
            int waveBase = 0;
            #pragma unroll
            for (int w = 0; w < 4; ++w) waveBase += (w < wid) ? ws[w] : 0;
            int o0 = segBase + waveBase + (P - p);
            int o1 = o0 + c0;
            if (i0 < range) { row[nLo + i0] = o0; lcur[i0] = o0; }
            if (i1 < range) { row[nLo + i1] = o1; lcur[i1] = o1; }
            if (nHi == n && tid == 0) row[n] = segEnd;
            __syncthreads();

            for (int t = segBase + tid; t < segEnd; t += 256) {
                u32 pr = pair[t];
                int pos = atomicAdd(&lcur[pr >> 17], 1);
                idx[pos] = (int)(pr & 0x1FFFFu);
            }
        }
    }
}

// ---------------------------------------------------------------------------
// Gather-mean over fp8(x16) 64 B rows -> bf16 means. HALF-WAVE (32 lanes)
// per node. R2 structure (best measured): 8 independent gather streams per
// iteration (32 edges/iter), 2 accumulator sets. Out-of-segment slots clamp
// branchlessly to a zeroed pad row at table index n; idx[] reads may overrun
// a segment end by <=28 slots -- always inside the workspace.
// ---------------------------------------------------------------------------
__global__ __launch_bounds__(256) void gather_mean_kernel(
    const u8* __restrict__ srcD, const u8* __restrict__ srcG,
    const int* __restrict__ rowD, const int* __restrict__ idxD,
    const int* __restrict__ rowG, const int* __restrict__ idxG,
    u16* __restrict__ outD, u16* __restrict__ outG, int nd, int ng)
{
    int hw = blockIdx.x * 8 + (threadIdx.x >> 5);   // half-wave id = node
    int l5 = threadIdx.x & 31;
    if (hw >= nd + ng) return;
    const bool isD = hw < nd;
    const int sub = l5 >> 3;        // 0..3: edge slot within a stream
    const int c8 = l5 & 7;          // uint2 index within 64 B row
    const u8* src; const int* row; const int* idx; u16* out; int node, npad;
    if (isD) { src = srcD; row = rowD; idx = idxD; out = outD; node = hw;      npad = ng; }
    else     { src = srcG; row = rowG; idx = idxG; out = outG; node = hw - nd; npad = nd; }
    int beg = row[node], end = row[node + 1];
    const u8* srcc = src + c8 * 8;  // hoist column offset into the base

    f32x2 aA[4], aB[4];
    #pragma unroll
    for (int j = 0; j < 4; ++j) {
        aA[j] = (f32x2){0.f, 0.f}; aB[j] = (f32x2){0.f, 0.f};
    }

    for (int i = beg; i < end; i += 32) {
        int p = i + sub;
        const int* ip = idx + p;
        // unconditional loads (branchless select below); overrun is benign
        int t0 = ip[0],  t1 = ip[4],  t2 = ip[8],  t3 = ip[12];
        int t4 = ip[16], t5 = ip[20], t6 = ip[24], t7 = ip[28];
        int s0 = (p      < end) ? t0 : npad;
        int s1 = (p + 4  < end) ? t1 : npad;
        int s2 = (p + 8  < end) ? t2 : npad;
        int s3 = (p + 12 < end) ? t3 : npad;
        int s4 = (p + 16 < end) ? t4 : npad;
        int s5 = (p + 20 < end) ? t5 : npad;
        int s6 = (p + 24 < end) ? t6 : npad;
        int s7 = (p + 28 < end) ? t7 : npad;
        uint2 v0 = *(const uint2*)(srcc + (size_t)s0 * 64);
        uint2 v1 = *(const uint2*)(srcc + (size_t)s1 * 64);
        uint2 v2 = *(const uint2*)(srcc + (size_t)s2 * 64);
        uint2 v3 = *(const uint2*)(srcc + (size_t)s3 * 64);
        uint2 v4 = *(const uint2*)(srcc + (size_t)s4 * 64);
        uint2 v5 = *(const uint2*)(srcc + (size_t)s5 * 64);
        uint2 v6 = *(const uint2*)(srcc + (size_t)s6 * 64);
        uint2 v7 = *(const uint2*)(srcc + (size_t)s7 * 64);
        aA[0] += __builtin_amdgcn_cvt_pk_f32_fp8((int)v0.x, false);
        aA[1] += __builtin_amdgcn_cvt_pk_f32_fp8((int)v0.x, true);
        aA[2] += __builtin_amdgcn_cvt_pk_f32_fp8((int)v0.y, false);
        aA[3] += __builtin_amdgcn_cvt_pk_f32_fp8((int)v0.y, true);
        aA[0] += __builtin_amdgcn_cvt_pk_f32_fp8((int)v1.x, false);
        aA[1] += __builtin_amdgcn_cvt_pk_f32_fp8((int)v1.x, true);
        aA[2] += __builtin_amdgcn_cvt_pk_f32_fp8((int)v1.y, false);
        aA[3] += __builtin_amdgcn_cvt_pk_f32_fp8((int)v1.y, true);
        aA[0] += __builtin_amdgcn_cvt_pk_f32_fp8((int)v2.x, false);
        aA[1] += __builtin_amdgcn_cvt_pk_f32_fp8((int)v2.x, true);
        aA[2] += __builtin_amdgcn_cvt_pk_f32_fp8((int)v2.y, false);
        aA[3] += __builtin_amdgcn_cvt_pk_f32_fp8((int)v2.y, true);
        aA[0] += __builtin_amdgcn_cvt_pk_f32_fp8((int)v3.x, false);
        aA[1] += __builtin_amdgcn_cvt_pk_f32_fp8((int)v3.x, true);
        aA[2] += __builtin_amdgcn_cvt_pk_f32_fp8((int)v3.y, false);
        aA[3] += __builtin_amdgcn_cvt_pk_f32_fp8((int)v3.y, true);
        aB[0] += __builtin_amdgcn_cvt_pk_f32_fp8((int)v4.x, false);
        aB[1] += __builtin_amdgcn_cvt_pk_f32_fp8((int)v4.x, true);
        aB[2] += __builtin_amdgcn_cvt_pk_f32_fp8((int)v4.y, false);
        aB[3] += __builtin_amdgcn_cvt_pk_f32_fp8((int)v4.y, true);
        aB[0] += __builtin_amdgcn_cvt_pk_f32_fp8((int)v5.x, false);
        aB[1] += __builtin_amdgcn_cvt_pk_f32_fp8((int)v5.x, true);
        aB[2] += __builtin_amdgcn_cvt_pk_f32_fp8((int)v5.y, false);
        aB[3] += __builtin_amdgcn_cvt_pk_f32_fp8((int)v5.y, true);
        aB[0] += __builtin_amdgcn_cvt_pk_f32_fp8((int)v6.x, false);
        aB[1] += __builtin_amdgcn_cvt_pk_f32_fp8((int)v6.x, true);
        aB[2] += __builtin_amdgcn_cvt_pk_f32_fp8((int)v6.y, false);
        aB[3] += __builtin_amdgcn_cvt_pk_f32_fp8((int)v6.y, true);
        aB[0] += __builtin_amdgcn_cvt_pk_f32_fp8((int)v7.x, false);
        aB[1] += __builtin_amdgcn_cvt_pk_f32_fp8((int)v7.x, true);
        aB[2] += __builtin_amdgcn_cvt_pk_f32_fp8((int)v7.y, false);
        aB[3] += __builtin_amdgcn_cvt_pk_f32_fp8((int)v7.y, true);
    }

    f32x2 acc[4];
    #pragma unroll
    for (int j = 0; j < 4; ++j) acc[j] = aA[j] + aB[j];
    #pragma unroll
    for (int j = 0; j < 4; ++j) {
        f32x2 t;
        t.x = __shfl_xor(acc[j].x, 8, 64);
        t.y = __shfl_xor(acc[j].y, 8, 64);
        acc[j] += t;
        t.x = __shfl_xor(acc[j].x, 16, 64);
        t.y = __shfl_xor(acc[j].y, 16, 64);
        acc[j] += t;
    }
    if (sub == 0) {
        float inv = 0.0625f / fmaxf((float)(end - beg), 1.0f);  // 1/16 descale
        u32 w0 = (u32)bf16rne(acc[0].x * inv) | ((u32)bf16rne(acc[0].y * inv) << 16);
        u32 w1 = (u32)bf16rne(acc[1].x * inv) | ((u32)bf16rne(acc[1].y * inv) << 16);
        u32 w2 = (u32)bf16rne(acc[2].x * inv) | ((u32)bf16rne(acc[2].y * inv) << 16);
        u32 w3 = (u32)bf16rne(acc[3].x * inv) | ((u32)bf16rne(acc[3].y * inv) << 16);
        uint4 pk = make_uint4(w0, w1, w2, w3);
        *(uint4*)(out + (size_t)node * H + c8 * 8) = pk;
    }
}

// ---------------------------------------------------------------------------
// SAGE linear via MFMA, BOTH directions in one dispatch.
// F8OUT: additionally emit the output rows as fp8(x16) 64 B rows (for the
// next layer's gather sources). Error: fp8 only feeds the mean path; the
// x-operand path stays bf16.
// ---------------------------------------------------------------------------
template <bool RELU, bool F8OUT>
__global__ __launch_bounds__(256) void sage_mm_mfma_kernel(
    const u16* __restrict__ meanD, const u16* __restrict__ xD, u16* __restrict__ outD,
    u8* __restrict__ outDf8,
    const float* __restrict__ wlD, const float* __restrict__ wrD,
    const float* __restrict__ bD, int nd,
    const u16* __restrict__ meanG, const u16* __restrict__ xG, u16* __restrict__ outG,
    u8* __restrict__ outGf8,
    const float* __restrict__ wlG, const float* __restrict__ wrG,
    const float* __restrict__ bG, int ng, int MBD)
{
    __shared__ u16 sB[16 * 64 * 8];   // [frag=c*4+t][lane][j]
    int b = blockIdx.x;
    const u16 *mean, *x; u16* out; u8* out8; const float *wl, *wr, *bias; int n;
    if (b < MBD) { mean = meanD; x = xD; out = outD; out8 = outDf8; wl = wlD; wr = wrD; bias = bD; n = nd; }
    else { b -= MBD; mean = meanG; x = xG; out = outG; out8 = outGf8; wl = wlG; wr = wrG; bias = bG; n = ng; }

    const int tid = threadIdx.x;
    for (int i = tid; i < 4096; i += 256) {
        int k = i >> 6, ncol = i & 63;
        int q = (k >> 3) & 3, j = k & 7, t = ncol >> 4, n15 = ncol & 15;
        int lane = q * 16 + n15;
        int c0 = k >> 5;                     // 0..1
        sB[(((c0 + 0) * 4 + t) * 64 + lane) * 8 + j] = bf16rne(wl[i]);
        sB[(((c0 + 2) * 4 + t) * 64 + lane) * 8 + j] = bf16rne(wr[i]);
    }
    __syncthreads();

    const int lane = tid & 63;
    const int wave = tid >> 6;
    const int m = lane & 15;
    const int q = lane >> 4;

    bf16x8 Bf[16];
    {
        const uint4* sB4 = (const uint4*)sB;
        #pragma unroll
        for (int f = 0; f < 16; ++f)
            Bf[f] = __builtin_bit_cast(bf16x8, sB4[f * 64 + lane]);
    }
    float bv[4];
    #pragma unroll
    for (int t = 0; t < 4; ++t) bv[t] = bias[t * 16 + m];

    const int row0 = b * 256;
    #pragma unroll
    for (int r = 0; r < 4; ++r) {
        int rbase = row0 + (wave + 4 * r) * 16;   // wave-uniform
        if (rbase >= n) break;
        int gr = min(rbase + m, n - 1);
        const uint4* mrow = (const uint4*)(mean + (size_t)gr * H);
        const uint4* xrow = (const uint4*)(x + (size_t)gr * H);
        bf16x8 A0 = __builtin_bit_cast(bf16x8, mrow[q]);
        bf16x8 A1 = __builtin_bit_cast(bf16x8, mrow[q + 4]);
        bf16x8 A2 = __builtin_bit_cast(bf16x8, xrow[q]);
        bf16x8 A3 = __builtin_bit_cast(bf16x8, xrow[q + 4]);
        f32x4 acc[4];
        #pragma unroll
        for (int t = 0; t < 4; ++t) acc[t] = (f32x4){bv[t], bv[t], bv[t], bv[t]};
        #pragma unroll
        for (int t = 0; t < 4; ++t) {
            acc[t] = __builtin_amdgcn_mfma_f32_16x16x32_bf16(A0, Bf[0 * 4 + t], acc[t], 0, 0, 0);
            acc[t] = __builtin_amdgcn_mfma_f32_16x16x32_bf16(A1, Bf[1 * 4 + t], acc[t], 0, 0, 0);
            acc[t] = __builtin_amdgcn_mfma_f32_16x16x32_bf16(A2, Bf[2 * 4 + t], acc[t], 0, 0, 0);
            acc[t] = __builtin_amdgcn_mfma_f32_16x16x32_bf16(A3, Bf[3 * 4 + t], acc[t], 0, 0, 0);
        }
        #pragma unroll
        for (int reg = 0; reg < 4; ++reg) {
            int orow = rbase + q * 4 + reg;
            if (orow < n) {
                u16* op = out + (size_t)orow * H;
                u8* op8 = F8OUT ? (out8 + (size_t)orow * H) : nullptr;
                #pragma unroll
                for (int t = 0; t < 4; ++t) {
                    float v = acc[t][reg];
                    if (RELU) v = fmaxf(v, 0.0f);
                    op[t * 16 + m] = bf16rne(v);
                    if (F8OUT) op8[t * 16 + m] = fp8enc(v * 16.0f);
                }
            }
        }
    }
}

// ---------------------------------------------------------------------------
// Classifier on bf16 rows: 8 lanes per edge, uint4 loads, fp32 dot,
// 3-stage xor reduce within the 8-lane group.
// ---------------------------------------------------------------------------
__global__ __launch_bounds__(256) void classify_kernel(
    const u16* __restrict__ hg2, const u16* __restrict__ hd2,
    const int* __restrict__ ls, const int* __restrict__ ld,
    float* __restrict__ out, int nl)
{
    long long t = (long long)blockIdx.x * blockDim.x + threadIdx.x;
    int e = (int)(t >> 3);
    int c8 = (int)(t & 7);
    if (e >= nl) return;
    int a = ls[e];
    int b = ld[e];
    uint4 ua = *((const uint4*)(hg2 + (size_t)a * H) + c8);
    uint4 ub = *((const uint4*)(hd2 + (size_t)b * H) + c8);
    float v = bflo(ua.x) * bflo(ub.x) + bfhi(ua.x) * bfhi(ub.x)
            + bflo(ua.y) * bflo(ub.y) + bfhi(ua.y) * bfhi(ub.y)
            + bflo(ua.z) * bflo(ub.z) + bfhi(ua.z) * bfhi(ub.z)
            + bflo(ua.w) * bflo(ub.w) + bfhi(ua.w) * bfhi(ub.w);
    v += __shfl_xor(v, 1, 64);
    v += __shfl_xor(v, 2, 64);
    v += __shfl_xor(v, 4, 64);
    if (c8 == 0) out[e] = v;
}

extern "C" void kernel_launch(void* const* d_in, const int* in_sizes, int n_in,
                              void* d_out, int out_size, void* d_ws, size_t ws_size,
                              hipStream_t stream)
{
    const float* gene  = (const float*)d_in[0];
    const float* dis   = (const float*)d_in[1];
    const float* w1gdl = (const float*)d_in[2];
    const float* w1gdr = (const float*)d_in[3];
    const float* w1dgl = (const float*)d_in[4];
    const float* w1dgr = (const float*)d_in[5];
    const float* w2gdl = (const float*)d_in[6];
    const float* w2gdr = (const float*)d_in[7];
    const float* w2dgl = (const float*)d_in[8];
    const float* w2dgr = (const float*)d_in[9];
    const float* b1gd  = (const float*)d_in[10];
    const float* b1dg  = (const float*)d_in[11];
    const float* b2gd  = (const float*)d_in[12];
    const float* b2dg  = (const float*)d_in[13];
    const int* es = (const int*)d_in[14];
    const int* ed = (const int*)d_in[15];
    const int* ls = (const int*)d_in[16];
    const int* ld = (const int*)d_in[17];

    const int ng = in_sizes[0] / H;   // 100000
    const int nd = in_sizes[1] / H;   // 30000
    const int ne = in_sizes[14];      // 1500000
    const int nl = in_sizes[16];      // 500000

    int shiftD = 0; while (((nd + (1 << shiftD) - 1) >> shiftD) > 256) ++shiftD;  // 7
    int shiftG = 0; while (((ng + (1 << shiftG) - 1) >> shiftG) > 256) ++shiftG;  // 9
    const int nbktD = (nd + (1 << shiftD) - 1) >> shiftD;
    const int nbktG = (ng + (1 << shiftG) - 1) >> shiftG;
    const int n1 = 256 * NB1;

    // --- Workspace layout ---
    int* rowD = (int*)d_ws;                         // nd+1
    int* rowG = rowD + nd + 1;                      // ng+1
    int* idxD = rowG + ng + 1;                      // ne
    int* idxG = idxD + ne;                          // ne
    u16* geneBf = (u16*)(idxG + ne);                // ng*H
    u16* disBf  = geneBf + (size_t)ng * H;          // nd*H
    u16* h1Dbf  = disBf + (size_t)nd * H;           // nd*H
    u16* h1Gbf  = h1Dbf + (size_t)nd * H;           // ng*H
    u16* h2Dbf  = h1Gbf + (size_t)ng * H;           // nd*H
    u16* h2Gbf  = h2Dbf + (size_t)nd * H;           // ng*H
    uintptr_t pf8 = (uintptr_t)(h2Gbf + (size_t)ng * H);
    pf8 = (pf8 + 15) & ~(uintptr_t)15;
    // fp8 tables each get ONE extra zeroed pad row (index n) as gather clamp
    u32* geneF8 = (u32*)pf8;                        // ng*16 + 16
    u32* disF8  = geneF8 + (size_t)ng * 16 + 16;    // nd*16 + 16
    u32* h1DF8  = disF8 + (size_t)nd * 16 + 16;     // nd*16 + 16
    u32* h1GF8  = h1DF8 + (size_t)nd * 16 + 16;     // ng*16 + 16
    uintptr_t p = (uintptr_t)(h1GF8 + (size_t)ng * 16 + 16);
    p = (p + 15) & ~(uintptr_t)15;
    // Union region: CSR-build scratch (dead after preproc) aliased w/ means.
    u16* MD = (u16*)p;                              // nd*H bf16 means
    u16* MG = MD + (size_t)nd * H;                  // ng*H
    int* histD = (int*)p;                           // n1
    int* histG = histD + n1;                        // n1
    int* baseD = histG + n1;                        // n1+1
    int* baseG = baseD + n1 + 1;                    // n1+1
    int* partial  = baseG + n1 + 1;                 // 1024
    uintptr_t pp = (uintptr_t)(partial + 1024);
    pp = (pp + 15) & ~(uintptr_t)15;
    u32* pairD = (u32*)pp;                          // ne
    u32* pairG = pairD + ne;                        // ne

    // --- Dispatch 1: edge histogram || table conversion (bf16 + fp8) ---
    const long long na4 = (long long)ng * H / 4;
    const long long nb4 = (long long)nd * H / 4;
    const int convBlocks = (int)((na4 + nb4 + 255) / 256);
    fused_count_convert_kernel<<<NB1 + convBlocks, 256, 0, stream>>>(
        es, ed, histD, histG, ne, shiftD, shiftG,
        gene, geneBf, geneF8, na4, dis, disBf, disF8, nb4);

    // --- Dispatch 2 (cooperative): scans + partition + CSR finalize ---
    {
        u32* pad0 = geneF8 + (size_t)ng * 16;
        u32* pad1 = disF8 + (size_t)nd * 16;
        u32* pad2 = h1DF8 + (size_t)nd * 16;
        u32* pad3 = h1GF8 + (size_t)ng * 16;
        int n1v = n1, nev = ne, sDv = shiftD, sGv = shiftG;
        int ndv = nd, ngv = ng, nbDv = nbktD, nbGv = nbktG;
        void* args[] = {
            &histD, &histG, &n1v, &baseD, &baseG,
            (void*)&es, (void*)&ed, &pairD, &pairG,
            &nev, &sDv, &sGv,
            &rowD, &idxD, &ndv, &nbDv,
            &rowG, &idxG, &ngv, &nbGv,
            &partial, &pad0, &pad1, &pad2, &pad3
        };
        hipLaunchCooperativeKernel((void*)preproc_coop_kernel,
                                   dim3(512), dim3(256), args, 0, stream);
    }

    const int gatherBlocks = (nd + ng + 7) / 8;
    const int MBD = (nd + 255) / 256;
    const int MBG = (ng + 255) / 256;

    // --- Layer 1: all-fp8 gather sources; mm emits bf16 + fp8 h1 ---
    gather_mean_kernel<<<gatherBlocks, 256, 0, stream>>>(
        (const u8*)geneF8, (const u8*)disF8, rowD, idxD, rowG, idxG, MD, MG, nd, ng);
    sage_mm_mfma_kernel<true, true><<<MBD + MBG, 256, 0, stream>>>(
        MD, disBf, h1Dbf, (u8*)h1DF8, w1gdl, w1gdr, b1gd, nd,
        MG, geneBf, h1Gbf, (u8*)h1GF8, w1dgl, w1dgr, b1dg, ng, MBD);

    // --- Layer 2: fp8 h1 gather sources; mm emits bf16 h2 only ---
    gather_mean_kernel<<<gatherBlocks, 256, 0, stream>>>(
        (const u8*)h1GF8, (const u8*)h1DF8, rowD, idxD, rowG, idxG, MD, MG, nd, ng);
    sage_mm_mfma_kernel<false, false><<<MBD + MBG, 256, 0, stream>>>(
        MD, h1Dbf, h2Dbf, nullptr, w2gdl, w2gdr, b2gd, nd,
        MG, h1Gbf, h2Gbf, nullptr, w2dgl, w2dgr, b2dg, ng, MBD);

    // --- Classifier ---
    {
        long long threads = (long long)nl * 8;
        int blocks = (int)((threads + 255) / 256);
        classify_kernel<<<blocks, 256, 0, stream>>>(h2Gbf, h2Dbf, ls, ld,
                                                    (float*)d_out, nl);
    }
}

// Round 8
// 307.369 us; speedup vs baseline: 1.6944x; 1.6944x over previous
//
#include <hip/hip_runtime.h>
#include <hip/hip_bf16.h>

#define H 64
#define SCAN_CHUNK 512
#define NB1 512          // edge partition blocks (hist = 256*NB1 per direction)

typedef unsigned short u16;
typedef unsigned int u32;
typedef unsigned char u8;
typedef __attribute__((ext_vector_type(8))) __bf16 bf16x8;
typedef __attribute__((ext_vector_type(4))) float f32x4;
typedef __attribute__((ext_vector_type(2))) float f32x2;

__device__ __forceinline__ float bflo(u32 u) {
    return __builtin_bit_cast(float, u << 16);
}
__device__ __forceinline__ float bfhi(u32 u) {
    return __builtin_bit_cast(float, u & 0xffff0000u);
}
__device__ __forceinline__ u16 bf16rne(float f) {
    u32 u = __builtin_bit_cast(u32, f);
    return (u16)((u + 0x7FFFu + ((u >> 16) & 1u)) >> 16);
}
__device__ __forceinline__ u8 fp8enc(float f) {   // OCP e4m3, input pre-scaled
    return (u8)(__builtin_amdgcn_cvt_pk_fp8_f32(f, 0.0f, 0, false) & 0xFF);
}

// ---------------------------------------------------------------------------
// Fused: blocks [0,NB1) = edge histogram (LDS atomics, bucket-major out);
// rest: table conversion gene/dis -> bf16 + fp8(x16, 64 B rows).
// R8: 512 threads/block -> 16 waves/CU for the latency-bound edge sweep
// (was 8). Hist cursors stay 256; init/writeout guarded to tid<256.
// ---------------------------------------------------------------------------
__global__ __launch_bounds__(512) void fused_count_convert_kernel(
    const int* __restrict__ es, const int* __restrict__ ed,
    int* __restrict__ histD, int* __restrict__ histG,
    int ne, int shiftD, int shiftG,
    const float* __restrict__ a, u16* __restrict__ oa, u32* __restrict__ oa8,
    long long na4,
    const float* __restrict__ b, u16* __restrict__ ob, u32* __restrict__ ob8,
    long long nb4)
{
    if (blockIdx.x < NB1) {
        __shared__ int lhd[256], lhg[256];
        const int tid = threadIdx.x;
        if (tid < 256) { lhd[tid] = 0; lhg[tid] = 0; }
        __syncthreads();
        const int chunk = (ne + NB1 - 1) / NB1;
        const int e0 = blockIdx.x * chunk;
        const int e1 = min(e0 + chunk, ne);
        for (int e = e0 + tid; e < e1; e += 512) {
            atomicAdd(&lhd[ed[e] >> shiftD], 1);
            atomicAdd(&lhg[es[e] >> shiftG], 1);
        }
        __syncthreads();
        if (tid < 256) {
            histD[tid * NB1 + blockIdx.x] = lhd[tid];
            histG[tid * NB1 + blockIdx.x] = lhg[tid];
        }
        return;
    }
    long long i = (long long)(blockIdx.x - NB1) * 512 + threadIdx.x;
    const float* src; u16* dst; u32* dst8; long long q;
    if (i < na4) { src = a; dst = oa; dst8 = oa8; q = i; }
    else if (i < na4 + nb4) { src = b; dst = ob; dst8 = ob8; q = i - na4; }
    else return;
    float4 v = *(const float4*)&src[q * 4];
    ushort4 o;
    o.x = bf16rne(v.x); o.y = bf16rne(v.y);
    o.z = bf16rne(v.z); o.w = bf16rne(v.w);
    *(ushort4*)&dst[q * 4] = o;
    int r = 0;
    r = __builtin_amdgcn_cvt_pk_fp8_f32(v.x * 16.0f, v.y * 16.0f, r, false);
    r = __builtin_amdgcn_cvt_pk_fp8_f32(v.z * 16.0f, v.w * 16.0f, r, true);
    dst8[q] = (u32)r;
}

// ---------------------------------------------------------------------------
// Scan phase A: per-block reduce of SCAN_CHUNK elements (2 segments).
// Block 0 additionally zeroes the four fp8 pad rows (gather clamp targets).
// ---------------------------------------------------------------------------
__global__ __launch_bounds__(256) void scan_reduce_kernel(
    const int* __restrict__ a1, int n1, const int* __restrict__ a2, int n2,
    int B1, int* __restrict__ partial,
    u32* __restrict__ pad0, u32* __restrict__ pad1,
    u32* __restrict__ pad2, u32* __restrict__ pad3)
{
    if (blockIdx.x == 0) {
        int tz = threadIdx.x;
        if (tz < 16) pad0[tz] = 0;
        else if (tz < 32) pad1[tz - 16] = 0;
        else if (tz < 48) pad2[tz - 32] = 0;
        else if (tz < 64) pad3[tz - 48] = 0;
    }
    const int b = blockIdx.x;
    const int* a; int n, base;
    if (b < B1) { a = a1; n = n1; base = b * SCAN_CHUNK; }
    else        { a = a2; n = n2; base = (b - B1) * SCAN_CHUNK; }
    int t = threadIdx.x;
    int i0 = base + 2 * t, i1 = i0 + 1;
    int v = ((i0 < n) ? a[i0] : 0) + ((i1 < n) ? a[i1] : 0);
    #pragma unroll
    for (int off = 32; off > 0; off >>= 1) v += __shfl_down(v, off, 64);
    __shared__ int ws[4];
    if ((t & 63) == 0) ws[t >> 6] = v;
    __syncthreads();
    if (t == 0) partial[b] = ws[0] + ws[1] + ws[2] + ws[3];
}

// ---------------------------------------------------------------------------
// Scan phase B+C merged: every block redundantly scans ALL partials (<=1024,
// L2-hot) in LDS to get its own offset, then scans its chunk and writes the
// cursor array. Block 0 also writes segment totals out1[n1]/out2[n2].
// ---------------------------------------------------------------------------
__global__ __launch_bounds__(256) void scan_apply_kernel(
    const int* __restrict__ a1, int* __restrict__ out1, int n1,
    const int* __restrict__ a2, int* __restrict__ out2, int n2,
    int B1, int nbtot, const int* __restrict__ partial)
{
    __shared__ int sExcl[1024];
    __shared__ int ws[4];
    const int tid = threadIdx.x;
    const int lane = tid & 63, wid = tid >> 6;

    int j0 = 4 * tid;
    int p0 = (j0 + 0 < nbtot) ? partial[j0 + 0] : 0;
    int p1 = (j0 + 1 < nbtot) ? partial[j0 + 1] : 0;
    int p2 = (j0 + 2 < nbtot) ? partial[j0 + 2] : 0;
    int p3 = (j0 + 3 < nbtot) ? partial[j0 + 3] : 0;
    int psum = p0 + p1 + p2 + p3;
    int P = psum;
    #pragma unroll
    for (int off = 1; off < 64; off <<= 1) {
        int u = __shfl_up(P, off, 64);
        if (lane >= off) P += u;
    }
    if (lane == 63) ws[wid] = P;
    __syncthreads();
    int wbase = 0;
    #pragma unroll
    for (int w = 0; w < 4; ++w) wbase += (w < wid) ? ws[w] : 0;
    int e = wbase + (P - psum);
    sExcl[j0 + 0] = e;
    sExcl[j0 + 1] = e + p0;
    sExcl[j0 + 2] = e + p0 + p1;
    sExcl[j0 + 3] = e + p0 + p1 + p2;
    __syncthreads();

    const int b = blockIdx.x;
    int tot1 = sExcl[B1 - 1] + partial[B1 - 1];
    int myOff = sExcl[b] - ((b >= B1) ? tot1 : 0);
    if (b == 0 && tid == 0) {
        int tot2 = sExcl[nbtot - 1] + partial[nbtot - 1] - tot1;
        out1[n1] = tot1;
        out2[n2] = tot2;
    }
    __syncthreads();

    const int* a; int* out; int n, base;
    if (b < B1) { a = a1; out = out1; n = n1; base = b * SCAN_CHUNK; }
    else        { a = a2; out = out2; n = n2; base = (b - B1) * SCAN_CHUNK; }
    int i0 = base + 2 * tid, i1 = i0 + 1;
    int x0 = (i0 < n) ? a[i0] : 0;
    int x1 = (i1 < n) ? a[i1] : 0;
    int p = x0 + x1;
    int Q = p;
    #pragma unroll
    for (int off = 1; off < 64; off <<= 1) {
        int u = __shfl_up(Q, off, 64);
        if (lane >= off) Q += u;
    }
    if (lane == 63) ws[wid] = Q;
    __syncthreads();
    int waveBase = 0;
    #pragma unroll
    for (int w = 0; w < 4; ++w) waveBase += (w < wid) ? ws[w] : 0;
    int off0 = myOff + waveBase + (Q - p);
    if (i0 < n) out[i0] = off0;
    if (i1 < n) out[i1] = off0 + x0;
}

// ---------------------------------------------------------------------------
// Partition pass 2: write packed (localkey<<17|other) u32s to per-(bucket,
// block) runs. LDS-atomic cursors only; runs contiguous & L2-resident.
// R8: 512 threads/block (16 waves/CU, was 8) -- edge sweep is latency-bound.
// ---------------------------------------------------------------------------
__global__ __launch_bounds__(512) void part_scatter_kernel(
    const int* __restrict__ es, const int* __restrict__ ed,
    const int* __restrict__ baseD, const int* __restrict__ baseG,
    u32* __restrict__ pairD, u32* __restrict__ pairG,
    int ne, int shiftD, int shiftG)
{
    __shared__ int curD[256], curG[256];
    const int tid = threadIdx.x;
    if (tid < 256) {
        curD[tid] = baseD[tid * NB1 + blockIdx.x];
        curG[tid] = baseG[tid * NB1 + blockIdx.x];
    }
    __syncthreads();
    const int maskD = (1 << shiftD) - 1;
    const int maskG = (1 << shiftG) - 1;
    const int chunk = (ne + NB1 - 1) / NB1;
    const int e0 = blockIdx.x * chunk;
    const int e1 = min(e0 + chunk, ne);
    for (int e = e0 + tid; e < e1; e += 512) {
        int s = es[e], d = ed[e];
        int pD = atomicAdd(&curD[d >> shiftD], 1);
        pairD[pD] = ((u32)(d & maskD) << 17) | (u32)s;
        int pG = atomicAdd(&curG[s >> shiftG], 1);
        pairG[pG] = ((u32)(s & maskG) << 17) | (u32)d;
    }
}

// ---------------------------------------------------------------------------
// CSR finalize: one block per bucket. LDS hist -> LDS scan -> row[]; second
// sweep ranks with LDS atomics, writes idx[]. No global atomics.
// R8: 512 threads/block for the two segment sweeps (latency-bound); the
// 512-element scan stays on tid<256 (2 elems/thread) with all-thread syncs.
// ---------------------------------------------------------------------------
__global__ __launch_bounds__(512) void csr_build_kernel(
    const u32* __restrict__ pairD, const int* __restrict__ baseD,
    int* __restrict__ rowD, int* __restrict__ idxD, int nd, int shiftD, int nbktD,
    const u32* __restrict__ pairG, const int* __restrict__ baseG,
    int* __restrict__ rowG, int* __restrict__ idxG, int ng, int shiftG, int nbktG)
{
    __shared__ int lcnt[512], lcur[512];
    __shared__ int ws[4];
    const int j = blockIdx.x & 255;
    const int isG = blockIdx.x >> 8;
    const u32* pair; const int* base; int* row; int* idx; int n, shift, nbkt;
    if (isG) { pair = pairG; base = baseG; row = rowG; idx = idxG; n = ng; shift = shiftG; nbkt = nbktG; }
    else     { pair = pairD; base = baseD; row = rowD; idx = idxD; n = nd; shift = shiftD; nbkt = nbktD; }
    if (j >= nbkt) return;

    const int tid = threadIdx.x;
    const int nLo = j << shift;
    const int nHi = min(nLo + (1 << shift), n);
    const int range = nHi - nLo;               // <= 512
    const int segBase = base[j * NB1];
    const int segEnd  = base[(j + 1) * NB1];

    lcnt[tid] = 0;
    __syncthreads();
    for (int t = segBase + tid; t < segEnd; t += 512)
        atomicAdd(&lcnt[pair[t] >> 17], 1);
    __syncthreads();

    const int lane = tid & 63, wid = tid >> 6;
    int i0 = 2 * tid, i1 = i0 + 1;
    int c0 = 0, c1 = 0, p = 0, P = 0;
    if (tid < 256) {
        c0 = (i0 < range) ? lcnt[i0] : 0;
        c1 = (i1 < range) ? lcnt[i1] : 0;
        p = c0 + c1;
        P = p;
        #pragma unroll
        for (int off = 1; off < 64; off <<= 1) {
            int u = __shfl_up(P, off, 64);
            if (lane >= off) P += u;
        }
        if (lane == 63) ws[wid] = P;
    }
    __syncthreads();
    if (tid < 256) {
        int waveBase = 0;
        #pragma unroll
        for (int w = 0; w < 4; ++w) waveBase += (w < wid) ? ws[w] : 0;
        int o0 = segBase + waveBase + (P - p);
        int o1 = o0 + c0;
        if (i0 < range) { row[nLo + i0] = o0; lcur[i0] = o0; }
        if (i1 < range) { row[nLo + i1] = o1; lcur[i1] = o1; }
        if (nHi == n && tid == 0) row[n] = segEnd;
    }
    __syncthreads();

    for (int t = segBase + tid; t < segEnd; t += 512) {
        u32 pr = pair[t];
        int pos = atomicAdd(&lcur[pr >> 17], 1);
        idx[pos] = (int)(pr & 0x1FFFFu);
    }
}

// ---------------------------------------------------------------------------
// Gather-mean over fp8(x16) 64 B rows -> bf16 means. HALF-WAVE (32 lanes)
// per node. R2 structure (best measured): 8 independent gather streams per
// iteration (32 edges/iter), 2 accumulator sets. Out-of-segment slots clamp
// branchlessly to a zeroed pad row at table index n; idx[] reads may overrun
// a segment end by <=28 slots -- always inside the workspace.
// ---------------------------------------------------------------------------
__global__ __launch_bounds__(256) void gather_mean_kernel(
    const u8* __restrict__ srcD, const u8* __restrict__ srcG,
    const int* __restrict__ rowD, const int* __restrict__ idxD,
    const int* __restrict__ rowG, const int* __restrict__ idxG,
    u16* __restrict__ outD, u16* __restrict__ outG, int nd, int ng)
{
    int hw = blockIdx.x * 8 + (threadIdx.x >> 5);   // half-wave id = node
    int l5 = threadIdx.x & 31;
    if (hw >= nd + ng) return;
    const bool isD = hw < nd;
    const int sub = l5 >> 3;        // 0..3: edge slot within a stream
    const int c8 = l5 & 7;          // uint2 index within 64 B row
    const u8* src; const int* row; const int* idx; u16* out; int node, npad;
    if (isD) { src = srcD; row = rowD; idx = idxD; out = outD; node = hw;      npad = ng; }
    else     { src = srcG; row = rowG; idx = idxG; out = outG; node = hw - nd; npad = nd; }
    int beg = row[node], end = row[node + 1];
    const u8* srcc = src + c8 * 8;  // hoist column offset into the base

    f32x2 aA[4], aB[4];
    #pragma unroll
    for (int j = 0; j < 4; ++j) {
        aA[j] = (f32x2){0.f, 0.f}; aB[j] = (f32x2){0.f, 0.f};
    }

    for (int i = beg; i < end; i += 32) {
        int p = i + sub;
        const int* ip = idx + p;
        // unconditional loads (branchless select below); overrun is benign
        int t0 = ip[0],  t1 = ip[4],  t2 = ip[8],  t3 = ip[12];
        int t4 = ip[16], t5 = ip[20], t6 = ip[24], t7 = ip[28];
        int s0 = (p      < end) ? t0 : npad;
        int s1 = (p + 4  < end) ? t1 : npad;
        int s2 = (p + 8  < end) ? t2 : npad;
        int s3 = (p + 12 < end) ? t3 : npad;
        int s4 = (p + 16 < end) ? t4 : npad;
        int s5 = (p + 20 < end) ? t5 : npad;
        int s6 = (p + 24 < end) ? t6 : npad;
        int s7 = (p + 28 < end) ? t7 : npad;
        uint2 v0 = *(const uint2*)(srcc + (size_t)s0 * 64);
        uint2 v1 = *(const uint2*)(srcc + (size_t)s1 * 64);
        uint2 v2 = *(const uint2*)(srcc + (size_t)s2 * 64);
        uint2 v3 = *(const uint2*)(srcc + (size_t)s3 * 64);
        uint2 v4 = *(const uint2*)(srcc + (size_t)s4 * 64);
        uint2 v5 = *(const uint2*)(srcc + (size_t)s5 * 64);
        uint2 v6 = *(const uint2*)(srcc + (size_t)s6 * 64);
        uint2 v7 = *(const uint2*)(srcc + (size_t)s7 * 64);
        aA[0] += __builtin_amdgcn_cvt_pk_f32_fp8((int)v0.x, false);
        aA[1] += __builtin_amdgcn_cvt_pk_f32_fp8((int)v0.x, true);
        aA[2] += __builtin_amdgcn_cvt_pk_f32_fp8((int)v0.y, false);
        aA[3] += __builtin_amdgcn_cvt_pk_f32_fp8((int)v0.y, true);
        aA[0] += __builtin_amdgcn_cvt_pk_f32_fp8((int)v1.x, false);
        aA[1] += __builtin_amdgcn_cvt_pk_f32_fp8((int)v1.x, true);
        aA[2] += __builtin_amdgcn_cvt_pk_f32_fp8((int)v1.y, false);
        aA[3] += __builtin_amdgcn_cvt_pk_f32_fp8((int)v1.y, true);
        aA[0] += __builtin_amdgcn_cvt_pk_f32_fp8((int)v2.x, false);
        aA[1] += __builtin_amdgcn_cvt_pk_f32_fp8((int)v2.x, true);
        aA[2] += __builtin_amdgcn_cvt_pk_f32_fp8((int)v2.y, false);
        aA[3] += __builtin_amdgcn_cvt_pk_f32_fp8((int)v2.y, true);
        aA[0] += __builtin_amdgcn_cvt_pk_f32_fp8((int)v3.x, false);
        aA[1] += __builtin_amdgcn_cvt_pk_f32_fp8((int)v3.x, true);
        aA[2] += __builtin_amdgcn_cvt_pk_f32_fp8((int)v3.y, false);
        aA[3] += __builtin_amdgcn_cvt_pk_f32_fp8((int)v3.y, true);
        aB[0] += __builtin_amdgcn_cvt_pk_f32_fp8((int)v4.x, false);
        aB[1] += __builtin_amdgcn_cvt_pk_f32_fp8((int)v4.x, true);
        aB[2] += __builtin_amdgcn_cvt_pk_f32_fp8((int)v4.y, false);
        aB[3] += __builtin_amdgcn_cvt_pk_f32_fp8((int)v4.y, true);
        aB[0] += __builtin_amdgcn_cvt_pk_f32_fp8((int)v5.x, false);
        aB[1] += __builtin_amdgcn_cvt_pk_f32_fp8((int)v5.x, true);
        aB[2] += __builtin_amdgcn_cvt_pk_f32_fp8((int)v5.y, false);
        aB[3] += __builtin_amdgcn_cvt_pk_f32_fp8((int)v5.y, true);
        aB[0] += __builtin_amdgcn_cvt_pk_f32_fp8((int)v6.x, false);
        aB[1] += __builtin_amdgcn_cvt_pk_f32_fp8((int)v6.x, true);
        aB[2] += __builtin_amdgcn_cvt_pk_f32_fp8((int)v6.y, false);
        aB[3] += __builtin_amdgcn_cvt_pk_f32_fp8((int)v6.y, true);
        aB[0] += __builtin_amdgcn_cvt_pk_f32_fp8((int)v7.x, false);
        aB[1] += __builtin_amdgcn_cvt_pk_f32_fp8((int)v7.x, true);
        aB[2] += __builtin_amdgcn_cvt_pk_f32_fp8((int)v7.y, false);
        aB[3] += __builtin_amdgcn_cvt_pk_f32_fp8((int)v7.y, true);
    }

    f32x2 acc[4];
    #pragma unroll
    for (int j = 0; j < 4; ++j) acc[j] = aA[j] + aB[j];
    #pragma unroll
    for (int j = 0; j < 4; ++j) {
        f32x2 t;
        t.x = __shfl_xor(acc[j].x, 8, 64);
        t.y = __shfl_xor(acc[j].y, 8, 64);
        acc[j] += t;
        t.x = __shfl_xor(acc[j].x, 16, 64);
        t.y = __shfl_xor(acc[j].y, 16, 64);
        acc[j] += t;
    }
    if (sub == 0) {
        float inv = 0.0625f / fmaxf((float)(end - beg), 1.0f);  // 1/16 descale
        u32 w0 = (u32)bf16rne(acc[0].x * inv) | ((u32)bf16rne(acc[0].y * inv) << 16);
        u32 w1 = (u32)bf16rne(acc[1].x * inv) | ((u32)bf16rne(acc[1].y * inv) << 16);
        u32 w2 = (u32)bf16rne(acc[2].x * inv) | ((u32)bf16rne(acc[2].y * inv) << 16);
        u32 w3 = (u32)bf16rne(acc[3].x * inv) | ((u32)bf16rne(acc[3].y * inv) << 16);
        uint4 pk = make_uint4(w0, w1, w2, w3);
        *(uint4*)(out + (size_t)node * H + c8 * 8) = pk;
    }
}

// ---------------------------------------------------------------------------
// SAGE linear via MFMA, BOTH directions in one dispatch.
// F8OUT: additionally emit the output rows as fp8(x16) 64 B rows (for the
// next layer's gather sources). Error: fp8 only feeds the mean path; the
// x-operand path stays bf16.
// ---------------------------------------------------------------------------
template <bool RELU, bool F8OUT>
__global__ __launch_bounds__(256) void sage_mm_mfma_kernel(
    const u16* __restrict__ meanD, const u16* __restrict__ xD, u16* __restrict__ outD,
    u8* __restrict__ outDf8,
    const float* __restrict__ wlD, const float* __restrict__ wrD,
    const float* __restrict__ bD, int nd,
    const u16* __restrict__ meanG, const u16* __restrict__ xG, u16* __restrict__ outG,
    u8* __restrict__ outGf8,
    const float* __restrict__ wlG, const float* __restrict__ wrG,
    const float* __restrict__ bG, int ng, int MBD)
{
    __shared__ u16 sB[16 * 64 * 8];   // [frag=c*4+t][lane][j]
    int b = blockIdx.x;
    const u16 *mean, *x; u16* out; u8* out8; const float *wl, *wr, *bias; int n;
    if (b < MBD) { mean = meanD; x = xD; out = outD; out8 = outDf8; wl = wlD; wr = wrD; bias = bD; n = nd; }
    else { b -= MBD; mean = meanG; x = xG; out = outG; out8 = outGf8; wl = wlG; wr = wrG; bias = bG; n = ng; }

    const int tid = threadIdx.x;
    for (int i = tid; i < 4096; i += 256) {
        int k = i >> 6, ncol = i & 63;
        int q = (k >> 3) & 3, j = k & 7, t = ncol >> 4, n15 = ncol & 15;
        int lane = q * 16 + n15;
        int c0 = k >> 5;                     // 0..1
        sB[(((c0 + 0) * 4 + t) * 64 + lane) * 8 + j] = bf16rne(wl[i]);
        sB[(((c0 + 2) * 4 + t) * 64 + lane) * 8 + j] = bf16rne(wr[i]);
    }
    __syncthreads();

    const int lane = tid & 63;
    const int wave = tid >> 6;
    const int m = lane & 15;
    const int q = lane >> 4;

    bf16x8 Bf[16];
    {
        const uint4* sB4 = (const uint4*)sB;
        #pragma unroll
        for (int f = 0; f < 16; ++f)
            Bf[f] = __builtin_bit_cast(bf16x8, sB4[f * 64 + lane]);
    }
    float bv[4];
    #pragma unroll
    for (int t = 0; t < 4; ++t) bv[t] = bias[t * 16 + m];

    const int row0 = b * 256;
    #pragma unroll
    for (int r = 0; r < 4; ++r) {
        int rbase = row0 + (wave + 4 * r) * 16;   // wave-uniform
        if (rbase >= n) break;
        int gr = min(rbase + m, n - 1);
        const uint4* mrow = (const uint4*)(mean + (size_t)gr * H);
        const uint4* xrow = (const uint4*)(x + (size_t)gr * H);
        bf16x8 A0 = __builtin_bit_cast(bf16x8, mrow[q]);
        bf16x8 A1 = __builtin_bit_cast(bf16x8, mrow[q + 4]);
        bf16x8 A2 = __builtin_bit_cast(bf16x8, xrow[q]);
        bf16x8 A3 = __builtin_bit_cast(bf16x8, xrow[q + 4]);
        f32x4 acc[4];
        #pragma unroll
        for (int t = 0; t < 4; ++t) acc[t] = (f32x4){bv[t], bv[t], bv[t], bv[t]};
        #pragma unroll
        for (int t = 0; t < 4; ++t) {
            acc[t] = __builtin_amdgcn_mfma_f32_16x16x32_bf16(A0, Bf[0 * 4 + t], acc[t], 0, 0, 0);
            acc[t] = __builtin_amdgcn_mfma_f32_16x16x32_bf16(A1, Bf[1 * 4 + t], acc[t], 0, 0, 0);
            acc[t] = __builtin_amdgcn_mfma_f32_16x16x32_bf16(A2, Bf[2 * 4 + t], acc[t], 0, 0, 0);
            acc[t] = __builtin_amdgcn_mfma_f32_16x16x32_bf16(A3, Bf[3 * 4 + t], acc[t], 0, 0, 0);
        }
        #pragma unroll
        for (int reg = 0; reg < 4; ++reg) {
            int orow = rbase + q * 4 + reg;
            if (orow < n) {
                u16* op = out + (size_t)orow * H;
                u8* op8 = F8OUT ? (out8 + (size_t)orow * H) : nullptr;
                #pragma unroll
                for (int t = 0; t < 4; ++t) {
                    float v = acc[t][reg];
                    if (RELU) v = fmaxf(v, 0.0f);
                    op[t * 16 + m] = bf16rne(v);
                    if (F8OUT) op8[t * 16 + m] = fp8enc(v * 16.0f);
                }
            }
        }
    }
}

// ---------------------------------------------------------------------------
// Classifier on bf16 rows: 8 lanes per edge, uint4 loads, fp32 dot,
// 3-stage xor reduce within the 8-lane group.
// ---------------------------------------------------------------------------
__global__ __launch_bounds__(256) void classify_kernel(
    const u16* __restrict__ hg2, const u16* __restrict__ hd2,
    const int* __restrict__ ls, const int* __restrict__ ld,
    float* __restrict__ out, int nl)
{
    long long t = (long long)blockIdx.x * blockDim.x + threadIdx.x;
    int e = (int)(t >> 3);
    int c8 = (int)(t & 7);
    if (e >= nl) return;
    int a = ls[e];
    int b = ld[e];
    uint4 ua = *((const uint4*)(hg2 + (size_t)a * H) + c8);
    uint4 ub = *((const uint4*)(hd2 + (size_t)b * H) + c8);
    float v = bflo(ua.x) * bflo(ub.x) + bfhi(ua.x) * bfhi(ub.x)
            + bflo(ua.y) * bflo(ub.y) + bfhi(ua.y) * bfhi(ub.y)
            + bflo(ua.z) * bflo(ub.z) + bfhi(ua.z) * bfhi(ub.z)
            + bflo(ua.w) * bflo(ub.w) + bfhi(ua.w) * bfhi(ub.w);
    v += __shfl_xor(v, 1, 64);
    v += __shfl_xor(v, 2, 64);
    v += __shfl_xor(v, 4, 64);
    if (c8 == 0) out[e] = v;
}

extern "C" void kernel_launch(void* const* d_in, const int* in_sizes, int n_in,
                              void* d_out, int out_size, void* d_ws, size_t ws_size,
                              hipStream_t stream)
{
    const float* gene  = (const float*)d_in[0];
    const float* dis   = (const float*)d_in[1];
    const float* w1gdl = (const float*)d_in[2];
    const float* w1gdr = (const float*)d_in[3];
    const float* w1dgl = (const float*)d_in[4];
    const float* w1dgr = (const float*)d_in[5];
    const float* w2gdl = (const float*)d_in[6];
    const float* w2gdr = (const float*)d_in[7];
    const float* w2dgl = (const float*)d_in[8];
    const float* w2dgr = (const float*)d_in[9];
    const float* b1gd  = (const float*)d_in[10];
    const float* b1dg  = (const float*)d_in[11];
    const float* b2gd  = (const float*)d_in[12];
    const float* b2dg  = (const float*)d_in[13];
    const int* es = (const int*)d_in[14];
    const int* ed = (const int*)d_in[15];
    const int* ls = (const int*)d_in[16];
    const int* ld = (const int*)d_in[17];

    const int ng = in_sizes[0] / H;   // 100000
    const int nd = in_sizes[1] / H;   // 30000
    const int ne = in_sizes[14];      // 1500000
    const int nl = in_sizes[16];      // 500000

    int shiftD = 0; while (((nd + (1 << shiftD) - 1) >> shiftD) > 256) ++shiftD;  // 7
    int shiftG = 0; while (((ng + (1 << shiftG) - 1) >> shiftG) > 256) ++shiftG;  // 9
    const int nbktD = (nd + (1 << shiftD) - 1) >> shiftD;
    const int nbktG = (ng + (1 << shiftG) - 1) >> shiftG;
    const int n1 = 256 * NB1;

    // --- Workspace layout ---
    int* rowD = (int*)d_ws;                         // nd+1
    int* rowG = rowD + nd + 1;                      // ng+1
    int* idxD = rowG + ng + 1;                      // ne
    int* idxG = idxD + ne;                          // ne
    u16* geneBf = (u16*)(idxG + ne);                // ng*H
    u16* disBf  = geneBf + (size_t)ng * H;          // nd*H
    u16* h1Dbf  = disBf + (size_t)nd * H;           // nd*H
    u16* h1Gbf  = h1Dbf + (size_t)nd * H;           // ng*H
    u16* h2Dbf  = h1Gbf + (size_t)ng * H;           // nd*H
    u16* h2Gbf  = h2Dbf + (size_t)nd * H;           // ng*H
    uintptr_t pf8 = (uintptr_t)(h2Gbf + (size_t)ng * H);
    pf8 = (pf8 + 15) & ~(uintptr_t)15;
    // fp8 tables each get ONE extra zeroed pad row (index n) as gather clamp
    u32* geneF8 = (u32*)pf8;                        // ng*16 + 16
    u32* disF8  = geneF8 + (size_t)ng * 16 + 16;    // nd*16 + 16
    u32* h1DF8  = disF8 + (size_t)nd * 16 + 16;     // nd*16 + 16
    u32* h1GF8  = h1DF8 + (size_t)nd * 16 + 16;     // ng*16 + 16
    uintptr_t p = (uintptr_t)(h1GF8 + (size_t)ng * 16 + 16);
    p = (p + 15) & ~(uintptr_t)15;
    // Union region: CSR-build scratch (dead after csr_build) aliased w/ means.
    u16* MD = (u16*)p;                              // nd*H bf16 means
    u16* MG = MD + (size_t)nd * H;                  // ng*H
    int* histD = (int*)p;                           // n1
    int* histG = histD + n1;                        // n1
    int* baseD = histG + n1;                        // n1+1
    int* baseG = baseD + n1 + 1;                    // n1+1
    int* partial  = baseG + n1 + 1;                 // 1024
    uintptr_t pp = (uintptr_t)(partial + 1024);
    pp = (pp + 15) & ~(uintptr_t)15;
    u32* pairD = (u32*)pp;                          // ne
    u32* pairG = pairD + ne;                        // ne

    // --- Dispatch 1: edge histogram || table conversion (bf16 + fp8) ---
    const long long na4 = (long long)ng * H / 4;
    const long long nb4 = (long long)nd * H / 4;
    const int convBlocks = (int)((na4 + nb4 + 511) / 512);
    fused_count_convert_kernel<<<NB1 + convBlocks, 512, 0, stream>>>(
        es, ed, histD, histG, ne, shiftD, shiftG,
        gene, geneBf, geneF8, na4, dis, disBf, disF8, nb4);

    // --- Dispatch 2-3: scans (2 segments); also zeroes fp8 pad rows ---
    const int B1 = n1 / SCAN_CHUNK;          // 256
    const int nbtot = 2 * B1;                // 512
    scan_reduce_kernel<<<nbtot, 256, 0, stream>>>(histD, n1, histG, n1, B1, partial,
                                                  geneF8 + (size_t)ng * 16,
                                                  disF8 + (size_t)nd * 16,
                                                  h1DF8 + (size_t)nd * 16,
                                                  h1GF8 + (size_t)ng * 16);
    scan_apply_kernel<<<nbtot, 256, 0, stream>>>(histD, baseD, n1,
                                                 histG, baseG, n1, B1, nbtot, partial);

    // --- Dispatch 4: edge pair partition (512 threads) ---
    part_scatter_kernel<<<NB1, 512, 0, stream>>>(es, ed, baseD, baseG,
                                                 pairD, pairG, ne, shiftD, shiftG);
    // --- Dispatch 5: CSR finalize (512 threads) ---
    csr_build_kernel<<<512, 512, 0, stream>>>(
        pairD, baseD, rowD, idxD, nd, shiftD, nbktD,
        pairG, baseG, rowG, idxG, ng, shiftG, nbktG);

    const int gatherBlocks = (nd + ng + 7) / 8;
    const int MBD = (nd + 255) / 256;
    const int MBG = (ng + 255) / 256;

    // --- Layer 1: all-fp8 gather sources; mm emits bf16 + fp8 h1 ---
    gather_mean_kernel<<<gatherBlocks, 256, 0, stream>>>(
        (const u8*)geneF8, (const u8*)disF8, rowD, idxD, rowG, idxG, MD, MG, nd, ng);
    sage_mm_mfma_kernel<true, true><<<MBD + MBG, 256, 0, stream>>>(
        MD, disBf, h1Dbf, (u8*)h1DF8, w1gdl, w1gdr, b1gd, nd,
        MG, geneBf, h1Gbf, (u8*)h1GF8, w1dgl, w1dgr, b1dg, ng, MBD);

    // --- Layer 2: fp8 h1 gather sources; mm emits bf16 h2 only ---
    gather_mean_kernel<<<gatherBlocks, 256, 0, stream>>>(
        (const u8*)h1GF8, (const u8*)h1DF8, rowD, idxD, rowG, idxG, MD, MG, nd, ng);
    sage_mm_mfma_kernel<false, false><<<MBD + MBG, 256, 0, stream>>>(
        MD, h1Dbf, h2Dbf, nullptr, w2gdl, w2gdr, b2gd, nd,
        MG, h1Gbf, h2Gbf, nullptr, w2dgl, w2dgr, b2dg, ng, MBD);

    // --- Classifier ---
    {
        long long threads = (long long)nl * 8;
        int blocks = (int)((threads + 255) / 256);
        classify_kernel<<<blocks, 256, 0, stream>>>(h2Gbf, h2Dbf, ls, ld,
                                                    (float*)d_out, nl);
    }
}